// Round 2
// baseline (324.125 us; speedup 1.0000x reference)
//
#include <hip/hip_runtime.h>
#include <hip/hip_bf16.h>

#define NN 4096

typedef __attribute__((ext_vector_type(8))) short short8;
typedef __attribute__((ext_vector_type(4))) float f32x4;

// fp32 -> bf16 round-to-nearest-even
static __device__ __forceinline__ unsigned short f2bf(float x) {
    unsigned int u = __float_as_uint(x);
    u += 0x7fffu + ((u >> 16) & 1u);
    return (unsigned short)(u >> 16);
}

// async global->LDS, 16 bytes per lane (dest = wave-uniform base + lane*16)
static __device__ __forceinline__ void load_lds16(const unsigned short* g, unsigned short* l) {
    __builtin_amdgcn_global_load_lds(
        (const __attribute__((address_space(1))) unsigned int*)g,
        (__attribute__((address_space(3))) unsigned int*)l,
        16, 0, 0);
}

// ---------------- fused pre-pass: convA + convB + zero-tiles in ONE launch ----------------
// blocks [0,16384)      : A -> bf16, tril mask (k<=i); skip k-regions the GEMM never reads
// blocks [16384,20480)  : B -> bf16 transposed, mask (k>=j); skip never-read blocks
// blocks [20480,21441)  : zero strict-upper tiles (496) + atomic-partial lower tiles d>=2 (465)
__global__ __launch_bounds__(256) void prep_all(const float* __restrict__ A,
                                                const float* __restrict__ B,
                                                unsigned short* __restrict__ Abf,
                                                unsigned short* __restrict__ Btb,
                                                float* __restrict__ C) {
    __shared__ float tile[64][65];
    const int b   = blockIdx.x;
    const int tid = threadIdx.x;

    if (b < 16384) {
        // ---- convA ----
        int t   = b * 256 + tid;
        int row = t >> 10;
        int c4  = (t & 1023) << 2;
        // GEMM reads Abf[row][k] only for k < (row_tile+1)*128
        int kmax = ((row >> 7) + 1) << 7;
        if (c4 < kmax) {
            const float4 v = *(const float4*)(A + ((size_t)row << 12) + c4);
            ushort4 o;
            o.x = (c4 + 0 <= row) ? f2bf(v.x) : (unsigned short)0;
            o.y = (c4 + 1 <= row) ? f2bf(v.y) : (unsigned short)0;
            o.z = (c4 + 2 <= row) ? f2bf(v.z) : (unsigned short)0;
            o.w = (c4 + 3 <= row) ? f2bf(v.w) : (unsigned short)0;
            *(ushort4*)(Abf + ((size_t)row << 12) + c4) = o;
        }
    } else if (b < 20480) {
        // ---- convB: Bt[n][k] = (k>=n) ? bf16(B[k][n]) : 0 ----
        const int b2 = b - 16384;
        const int n0 = (b2 & 63) << 6;
        const int k0 = (b2 >> 6) << 6;
        // GEMM reads Btb[n][k] only for k >= (n_tile)*128
        if (k0 < ((n0 >> 7) << 7)) return;
        #pragma unroll
        for (int p = 0; p < 4; ++p) {
            int idx = p * 256 + tid;
            int kr  = idx >> 4;
            int c4  = (idx & 15) << 2;
            const float4 v = *(const float4*)(B + (size_t)(k0 + kr) * NN + n0 + c4);
            tile[kr][c4 + 0] = v.x; tile[kr][c4 + 1] = v.y;
            tile[kr][c4 + 2] = v.z; tile[kr][c4 + 3] = v.w;
        }
        __syncthreads();
        #pragma unroll
        for (int p = 0; p < 4; ++p) {
            int idx = p * 256 + tid;
            int nr  = idx >> 4;
            int k4  = (idx & 15) << 2;
            int gn  = n0 + nr;
            ushort4 o;
            o.x = (k0 + k4 + 0 >= gn) ? f2bf(tile[k4 + 0][nr]) : (unsigned short)0;
            o.y = (k0 + k4 + 1 >= gn) ? f2bf(tile[k4 + 1][nr]) : (unsigned short)0;
            o.z = (k0 + k4 + 2 >= gn) ? f2bf(tile[k4 + 2][nr]) : (unsigned short)0;
            o.w = (k0 + k4 + 3 >= gn) ? f2bf(tile[k4 + 3][nr]) : (unsigned short)0;
            *(ushort4*)(Btb + (size_t)gn * NN + k0 + k4) = o;
        }
    } else {
        // ---- zero tiles ----
        const int t = b - 20480;
        int bi, bj;
        if (t < 496) {
            // strict-upper tiles
            int u = t;
            int e = (int)((sqrtf(8.f * (float)u + 1.f) - 1.f) * 0.5f);
            while ((e + 1) * (e + 2) / 2 <= u) ++e;
            while (e * (e + 1) / 2 > u) --e;
            int r = u - e * (e + 1) / 2;
            bi = r; bj = e + 1;
        } else {
            // lower tiles with d >= 2 (these receive atomicAdd partials)
            int u = t - 496;
            int d = 2;
            for (; d < 32; ++d) { int cnt = 32 - d; if (u < cnt) break; u -= cnt; }
            bj = u; bi = u + d;
        }
        const float4 z = make_float4(0.f, 0.f, 0.f, 0.f);
        #pragma unroll
        for (int it = 0; it < 16; ++it) {
            int idx = it * 256 + tid;
            int rr  = idx >> 5;
            int c4  = (idx & 31) << 2;
            *(float4*)&C[(size_t)(bi * 128 + rr) * NN + bj * 128 + c4] = z;
        }
    }
}

// ---------------- main GEMM: 128x128 tile, BK=32, uniform split-K (<=8 steps/unit) ----------------
// grid = 3128 units: tile (bi,bj), d=bi-bj, m=ceil((d+1)/2) chunks of <=8 K-steps (K=256).
// Single 16KB LDS buffer, 2-barrier loop; latency hidden by ~8 resident blocks/CU + backfill
// queue (3128 blocks > ~2048 resident capacity). Longest-work-first so the queue drains clean.
__global__ __launch_bounds__(256, 4) void gemm_tril_sk(const unsigned short* __restrict__ Abf,
                                                       const unsigned short* __restrict__ Btb,
                                                       float* __restrict__ C) {
    const int tid = threadIdx.x;

    // decode reversed index -> (d desc, tile, chunk): deepest units dispatch first
    int u = 3127 - (int)blockIdx.x, d, m = 1;
    for (d = 31; d >= 0; --d) {
        m = (d + 2) >> 1;                       // ceil((d+1)/2)
        int cnt = (32 - d) * m;
        if (u < cnt) break;
        u -= cnt;
    }
    const int blk = u / m;
    const int c   = u - blk * m;
    const int bj = blk, bi = blk + d;

    __shared__ __attribute__((aligned(16))) unsigned short As[128 * 32];
    __shared__ __attribute__((aligned(16))) unsigned short Bs[128 * 32];

    const int lane = tid & 63;
    const int w    = tid >> 6;
    const int wm   = w >> 1, wn = w & 1;
    const int l15  = lane & 15, quad = lane >> 4;

    f32x4 acc[4][4];
    const f32x4 zero4 = {0.f, 0.f, 0.f, 0.f};
    #pragma unroll
    for (int i = 0; i < 4; ++i)
        #pragma unroll
        for (int j = 0; j < 4; ++j) acc[i][j] = zero4;

    const int kbB = (bj << 2) + c * 8;
    const int kbE = min(kbB + 8, (bi << 2) + 4);    // exclusive; 4 or 8 steps

    // per-thread staging addresses
    const int rowA = tid >> 2;
    const int q    = tid & 3;
    const unsigned short* Ab = Abf + (size_t)(bi * 128 + rowA) * NN + q * 8;
    const unsigned short* Bb = Btb + (size_t)(bj * 128 + rowA) * NN + q * 8;

    for (int kb = kbB; kb < kbE; ++kb) {
        const int koff = kb << 5;
        load_lds16(Ab + koff,                   &As[tid * 8]);
        load_lds16(Bb + koff,                   &Bs[tid * 8]);
        load_lds16(Ab + (size_t)64 * NN + koff, &As[(256 + tid) * 8]);
        load_lds16(Bb + (size_t)64 * NN + koff, &Bs[(256 + tid) * 8]);
        __syncthreads();

        short8 a[4], bfr[4];
        #pragma unroll
        for (int mt = 0; mt < 4; ++mt)
            a[mt] = *(const short8*)&As[(wm * 64 + mt * 16 + l15) * 32 + quad * 8];
        #pragma unroll
        for (int nt = 0; nt < 4; ++nt)
            bfr[nt] = *(const short8*)&Bs[(wn * 64 + nt * 16 + l15) * 32 + quad * 8];
        #pragma unroll
        for (int mt = 0; mt < 4; ++mt)
            #pragma unroll
            for (int nt = 0; nt < 4; ++nt)
                acc[mt][nt] = __builtin_amdgcn_mfma_f32_16x16x32_bf16(a[mt], bfr[nt], acc[mt][nt], 0, 0, 0);
        __syncthreads();
    }

    // epilogue: C/D layout col=lane&15, row=quad*4+reg (m89-verified)
    if (m == 1) {
        // d<=1: sole owner, direct store (mask only needed on the diagonal d==0)
        #pragma unroll
        for (int mt = 0; mt < 4; ++mt) {
            #pragma unroll
            for (int nt = 0; nt < 4; ++nt) {
                const int gj  = bj * 128 + wn * 64 + nt * 16 + l15;
                const int gi0 = bi * 128 + wm * 64 + mt * 16 + quad * 4;
                #pragma unroll
                for (int rr = 0; rr < 4; ++rr) {
                    int gi = gi0 + rr;
                    float v = acc[mt][nt][rr];
                    C[(size_t)gi * NN + gj] = (d > 0 || gi >= gj) ? v : 0.f;
                }
            }
        }
    } else {
        // partial contribution: tile pre-zeroed; d>=2 so strictly lower, no mask
        #pragma unroll
        for (int mt = 0; mt < 4; ++mt) {
            #pragma unroll
            for (int nt = 0; nt < 4; ++nt) {
                const int gj  = bj * 128 + wn * 64 + nt * 16 + l15;
                const int gi0 = bi * 128 + wm * 64 + mt * 16 + quad * 4;
                #pragma unroll
                for (int rr = 0; rr < 4; ++rr) {
                    int gi = gi0 + rr;
                    atomicAdd(&C[(size_t)gi * NN + gj], acc[mt][nt][rr]);
                }
            }
        }
    }
}

// ---------------- fallback (ws too small): fp32 LDS-tiled, correct-but-slow ----------------
__global__ void gemm_fallback(const float* __restrict__ A, const float* __restrict__ B,
                              float* __restrict__ C) {
    const int bi = blockIdx.y, bj = blockIdx.x;
    const int ty = threadIdx.y, tx = threadIdx.x;
    const int gi = bi * 32 + ty, gj = bj * 32 + tx;
    if (bi < bj) { C[(size_t)gi * NN + gj] = 0.f; return; }
    __shared__ float As[32][33], Bs[32][33];
    float s = 0.f;
    for (int kt = bj; kt <= bi; ++kt) {
        const int k = kt * 32;
        float av = A[(size_t)gi * NN + k + tx];
        As[ty][tx] = (k + tx <= gi) ? av : 0.f;
        float bv = B[(size_t)(k + ty) * NN + gj];
        Bs[ty][tx] = (k + ty >= gj) ? bv : 0.f;
        __syncthreads();
        #pragma unroll
        for (int kk = 0; kk < 32; ++kk) s += As[ty][kk] * Bs[kk][tx];
        __syncthreads();
    }
    C[(size_t)gi * NN + gj] = (gi >= gj) ? s : 0.f;
}

extern "C" void kernel_launch(void* const* d_in, const int* in_sizes, int n_in,
                              void* d_out, int out_size, void* d_ws, size_t ws_size,
                              hipStream_t stream) {
    const float* A = (const float*)d_in[0];
    const float* B = (const float*)d_in[1];
    float* C = (float*)d_out;

    const size_t need = (size_t)2 * NN * NN * sizeof(unsigned short);  // 64 MB
    if (ws_size >= need) {
        unsigned short* Abf = (unsigned short*)d_ws;
        unsigned short* Btb = Abf + (size_t)NN * NN;
        prep_all<<<dim3(21441), dim3(256), 0, stream>>>(A, B, Abf, Btb, C);
        gemm_tril_sk<<<dim3(3128), dim3(256), 0, stream>>>(Abf, Btb, C);
    } else {
        gemm_fallback<<<dim3(128, 128), dim3(32, 32), 0, stream>>>(A, B, C);
    }
}

// Round 3
// 272.489 us; speedup vs baseline: 1.1895x; 1.1895x over previous
//
#include <hip/hip_runtime.h>

#define NN 4096

typedef __attribute__((ext_vector_type(8))) short short8;
typedef __attribute__((ext_vector_type(4))) float f32x4;

// fp32 -> bf16 round-to-nearest-even
static __device__ __forceinline__ unsigned short f2bf(float x) {
    unsigned int u = __float_as_uint(x);
    u += 0x7fffu + ((u >> 16) & 1u);
    return (unsigned short)(u >> 16);
}

// async global->LDS, 16 bytes per lane (dest = wave-uniform base + lane*16)
static __device__ __forceinline__ void load_lds16(const unsigned short* g, unsigned short* l) {
    __builtin_amdgcn_global_load_lds(
        (const __attribute__((address_space(1))) unsigned int*)g,
        (__attribute__((address_space(3))) unsigned int*)l,
        16, 0, 0);
}

// XOR-swizzled byte offset inside one 16KB K-step tile (256 rows x 32 k bf16, row = 64B).
// phys = logical ^ (((logical>>7)&7)<<4): involution, permutes 16B chunks within 128B pairs.
// ds_read_b128 column reads (16 rows, stride 64B) hit 8 distinct 16B slots -> 2-way (free).
static __device__ __forceinline__ int swz_byte(int row, int byte_in_row) {
    return (row * 64 + byte_in_row) ^ (((row >> 1) & 7) << 4);
}

// ---------------- fused pre-pass: pack A & B into tiled+swizzled bf16 + zero C tiles ----------------
// A2 layout: [bi(16)][kb(128)][16KB tile of 256 rows x 32 k], only kb < (bi+1)*8 written.
// B2 layout: [bjn(16)][kb(128)][16KB tile of 256 n-rows x 32 k] (B transposed), kb >= bjn*8.
// blocks [0,1088): A pack; [1088,2176): B pack; [2176,2374): zero C tiles.
__global__ __launch_bounds__(256) void prep_all(const float* __restrict__ A,
                                                const float* __restrict__ B,
                                                unsigned short* __restrict__ A2,
                                                unsigned short* __restrict__ B2,
                                                float* __restrict__ C) {
    __shared__ float tile[32][260];
    const int b   = blockIdx.x;
    const int tid = threadIdx.x;

    if (b < 1088) {
        // ---- pack A tile (bi, kb): rows bi*256..+255, k = kb*32..+31, mask k<=i ----
        int rem = b, bi;
        for (bi = 0; bi < 16; ++bi) { int cnt = (bi + 1) * 8; if (rem < cnt) break; rem -= cnt; }
        const int kb = rem;
        unsigned short* out = A2 + (size_t)bi * 1048576 + (size_t)kb * 8192;
        #pragma unroll
        for (int p = 0; p < 8; ++p) {
            int id  = p * 256 + tid;
            int row = id >> 3;               // 0..255
            int c4  = (id & 7) << 2;         // 0..28 (k within tile)
            const int gi = bi * 256 + row;
            const int kg = kb * 32 + c4;
            const float4 v = *(const float4*)(A + (size_t)gi * NN + kg);
            ushort4 o;
            o.x = (kg + 0 <= gi) ? f2bf(v.x) : (unsigned short)0;
            o.y = (kg + 1 <= gi) ? f2bf(v.y) : (unsigned short)0;
            o.z = (kg + 2 <= gi) ? f2bf(v.z) : (unsigned short)0;
            o.w = (kg + 3 <= gi) ? f2bf(v.w) : (unsigned short)0;
            *(ushort4*)&out[swz_byte(row, c4 * 2) >> 1] = o;
        }
    } else if (b < 2176) {
        // ---- pack B tile (bjn, kb): n rows bjn*256..+255, k = kb*32..+31, mask k>=n ----
        int rem = b - 1088, bjn;
        for (bjn = 0; bjn < 16; ++bjn) { int cnt = 128 - bjn * 8; if (rem < cnt) break; rem -= cnt; }
        const int kb = bjn * 8 + rem;
        // stage 32(k) x 256(n) f32 block of B, coalesced
        #pragma unroll
        for (int p = 0; p < 8; ++p) {
            int id   = p * 256 + tid;
            int krow = id >> 6;              // 0..31
            int c4   = (id & 63) << 2;       // 0..252
            const float4 v = *(const float4*)(B + (size_t)(kb * 32 + krow) * NN + bjn * 256 + c4);
            tile[krow][c4 + 0] = v.x; tile[krow][c4 + 1] = v.y;
            tile[krow][c4 + 2] = v.z; tile[krow][c4 + 3] = v.w;
        }
        __syncthreads();
        unsigned short* out = B2 + (size_t)bjn * 1048576 + (size_t)kb * 8192;
        const int n  = tid;                  // 0..255
        const int ng = bjn * 256 + n;
        #pragma unroll
        for (int kc = 0; kc < 4; ++kc) {
            short8 o;
            #pragma unroll
            for (int e = 0; e < 8; ++e) {
                int kg = kb * 32 + kc * 8 + e;
                o[e] = (kg >= ng) ? (short)f2bf(tile[kc * 8 + e][n]) : (short)0;
            }
            *(short8*)&out[swz_byte(n, kc * 16) >> 1] = o;
        }
    } else {
        // ---- zero C tiles: 120 strict-upper 256-tiles + 78 split lower tiles (D>=4) ----
        int u = b - 2176;
        int ti, tj;
        if (u < 120) {
            for (tj = 1; tj < 16; ++tj) { if (u < tj) { ti = u; break; } u -= tj; }
        } else {
            u -= 120;
            int d2;
            for (d2 = 4; d2 < 16; ++d2) { int cnt = 16 - d2; if (u < cnt) break; u -= cnt; }
            tj = u; ti = u + d2;
        }
        const float4 z = make_float4(0.f, 0.f, 0.f, 0.f);
        #pragma unroll
        for (int it = 0; it < 64; ++it) {
            int idx = it * 256 + tid;
            int rr  = idx >> 6;              // 0..255
            int c4  = (idx & 63) << 2;       // 0..252
            *(float4*)&C[(size_t)(ti * 256 + rr) * NN + tj * 256 + c4] = z;
        }
    }
}

// ---------------- main GEMM: 256x256 tile, 8 waves (2x4), BK=32, split-K <=32 steps ----------------
// 260 units: tile (bi,bj) D=bi-bj in 256-units, m=ceil((D+1)/4) balanced chunks.
// Staging = one contiguous 16KB burst per matrix per K-step (packed layout), swizzled ds_reads.
__global__ __launch_bounds__(512, 2) void gemm_tril(const unsigned short* __restrict__ A2,
                                                    const unsigned short* __restrict__ B2,
                                                    float* __restrict__ C) {
    const int tid = threadIdx.x;

    // bijective XCD-chunked map: blocks on one XCD get a contiguous run of units
    const int bidx = (int)blockIdx.x;
    const int xcd = bidx & 7, ix = bidx >> 3;
    int u = (xcd < 4 ? xcd * 33 : 132 + (xcd - 4) * 32) + ix;

    // decode unit (sorted deepest-D first) -> (D, tile, chunk)
    int D, m = 1, rem = u;
    for (D = 15; D >= 0; --D) {
        m = (D + 4) >> 2;                    // ceil((D+1)/4)
        int cnt = (16 - D) * m;
        if (rem < cnt) break;
        rem -= cnt;
    }
    const int blk = rem / m;
    const int c   = rem - blk * m;
    const int bj = blk, bi = blk + D;
    const int S   = (D + 1) * 8;             // total K-steps of this tile
    const int kb0 = bj * 8 + (c * S) / m;
    const int kb1 = bj * 8 + ((c + 1) * S) / m;

    __shared__ __attribute__((aligned(16))) unsigned short As[256 * 32];
    __shared__ __attribute__((aligned(16))) unsigned short Bs[256 * 32];

    const int lane = tid & 63;
    const int w    = tid >> 6;               // 0..7
    const int wm   = w >> 2, wn = w & 3;     // 2 x 4 wave grid: 128 x 64 per wave
    const int l15  = lane & 15, quad = lane >> 4;

    f32x4 acc[8][4];
    const f32x4 zero4 = {0.f, 0.f, 0.f, 0.f};
    #pragma unroll
    for (int i = 0; i < 8; ++i)
        #pragma unroll
        for (int j = 0; j < 4; ++j) acc[i][j] = zero4;

    const unsigned short* Atile = A2 + (size_t)bi * 1048576 + tid * 8;
    const unsigned short* Btile = B2 + (size_t)bj * 1048576 + tid * 8;

    for (int kb = kb0; kb < kb1; ++kb) {
        const unsigned short* ga = Atile + kb * 8192;
        const unsigned short* gb = Btile + kb * 8192;
        load_lds16(ga,        &As[tid * 8]);
        load_lds16(ga + 4096, &As[4096 + tid * 8]);
        load_lds16(gb,        &Bs[tid * 8]);
        load_lds16(gb + 4096, &Bs[4096 + tid * 8]);
        __syncthreads();

        short8 a[8], bq[4];
        #pragma unroll
        for (int mt = 0; mt < 8; ++mt) {
            int r = wm * 128 + mt * 16 + l15;
            a[mt] = *(const short8*)&As[swz_byte(r, quad * 16) >> 1];
        }
        #pragma unroll
        for (int nt = 0; nt < 4; ++nt) {
            int r = wn * 64 + nt * 16 + l15;
            bq[nt] = *(const short8*)&Bs[swz_byte(r, quad * 16) >> 1];
        }
        #pragma unroll
        for (int mt = 0; mt < 8; ++mt)
            #pragma unroll
            for (int nt = 0; nt < 4; ++nt)
                acc[mt][nt] = __builtin_amdgcn_mfma_f32_16x16x32_bf16(a[mt], bq[nt], acc[mt][nt], 0, 0, 0);
        __syncthreads();
    }

    // epilogue: C/D layout col=lane&15, row=quad*4+reg (m89-verified)
    if (m == 1) {
        // D<=3: sole owner, direct store (diagonal mask only when D==0)
        #pragma unroll
        for (int mt = 0; mt < 8; ++mt) {
            #pragma unroll
            for (int nt = 0; nt < 4; ++nt) {
                const int gj  = bj * 256 + wn * 64 + nt * 16 + l15;
                const int gi0 = bi * 256 + wm * 128 + mt * 16 + quad * 4;
                #pragma unroll
                for (int rr = 0; rr < 4; ++rr) {
                    int gi = gi0 + rr;
                    float v = acc[mt][nt][rr];
                    C[(size_t)gi * NN + gj] = (D > 0 || gi >= gj) ? v : 0.f;
                }
            }
        }
    } else {
        // partial contribution: tile pre-zeroed; D>=4 so strictly lower, no mask
        #pragma unroll
        for (int mt = 0; mt < 8; ++mt) {
            #pragma unroll
            for (int nt = 0; nt < 4; ++nt) {
                const int gj  = bj * 256 + wn * 64 + nt * 16 + l15;
                const int gi0 = bi * 256 + wm * 128 + mt * 16 + quad * 4;
                #pragma unroll
                for (int rr = 0; rr < 4; ++rr) {
                    int gi = gi0 + rr;
                    atomicAdd(&C[(size_t)gi * NN + gj], acc[mt][nt][rr]);
                }
            }
        }
    }
}

// ---------------- fallback (ws too small): fp32 LDS-tiled, correct-but-slow ----------------
__global__ void gemm_fallback(const float* __restrict__ A, const float* __restrict__ B,
                              float* __restrict__ C) {
    const int bi = blockIdx.y, bj = blockIdx.x;
    const int ty = threadIdx.y, tx = threadIdx.x;
    const int gi = bi * 32 + ty, gj = bj * 32 + tx;
    if (bi < bj) { C[(size_t)gi * NN + gj] = 0.f; return; }
    __shared__ float As[32][33], Bs[32][33];
    float s = 0.f;
    for (int kt = bj; kt <= bi; ++kt) {
        const int k = kt * 32;
        float av = A[(size_t)gi * NN + k + tx];
        As[ty][tx] = (k + tx <= gi) ? av : 0.f;
        float bv = B[(size_t)(k + ty) * NN + gj];
        Bs[ty][tx] = (k + ty >= gj) ? bv : 0.f;
        __syncthreads();
        #pragma unroll
        for (int kk = 0; kk < 32; ++kk) s += As[ty][kk] * Bs[kk][tx];
        __syncthreads();
    }
    C[(size_t)gi * NN + gj] = (gi >= gj) ? s : 0.f;
}

extern "C" void kernel_launch(void* const* d_in, const int* in_sizes, int n_in,
                              void* d_out, int out_size, void* d_ws, size_t ws_size,
                              hipStream_t stream) {
    const float* A = (const float*)d_in[0];
    const float* B = (const float*)d_in[1];
    float* C = (float*)d_out;

    const size_t need = (size_t)2 * NN * NN * sizeof(unsigned short);  // 64 MB
    if (ws_size >= need) {
        unsigned short* A2 = (unsigned short*)d_ws;
        unsigned short* B2 = A2 + (size_t)NN * NN;
        prep_all<<<dim3(2374), dim3(256), 0, stream>>>(A, B, A2, B2, C);
        gemm_tril<<<dim3(260), dim3(512), 0, stream>>>(A2, B2, C);
    } else {
        gemm_fallback<<<dim3(128, 128), dim3(32, 32), 0, stream>>>(A, B, C);
    }
}